// Round 1
// baseline (1304.383 us; speedup 1.0000x reference)
//
#include <hip/hip_runtime.h>
#include <hip/hip_bf16.h>
#include <math.h>

// ---------------------------------------------------------------------------
// ChebNet (K=3) two-layer forward, restructured:
//   cheb(x,W) = x@W0 - x@W2 + P(x@W1 + 2*P(x@W2)) + b,  P = edge scatter-sum
// P is applied in output feature space (64 then 40 dims).
// Edge scatter is converted to CSR-by-dst gather (built per launch).
// ---------------------------------------------------------------------------

#define FIN1 128
#define HID 64
#define NCLS 40

__global__ void k_zero(int* __restrict__ p, int n) {
    int i = blockIdx.x * blockDim.x + threadIdx.x;
    if (i < n) p[i] = 0;
}

__global__ void k_count(const int* __restrict__ dst, int E, int* __restrict__ count) {
    int e = blockIdx.x * blockDim.x + threadIdx.x;
    if (e < E) atomicAdd(&count[dst[e]], 1);
}

// Single-block exclusive scan over N counts -> row_ptr, cursor; also deg->dis.
__global__ __launch_bounds__(1024) void k_scan(const int* __restrict__ count, int N,
                                               int* __restrict__ row_ptr,
                                               int* __restrict__ cursor,
                                               float* __restrict__ dis) {
    __shared__ int sums[1024];
    int tid = threadIdx.x;
    int per = (N + 1023) / 1024;
    int start = tid * per;
    int end = min(start + per, N);
    int s = 0;
    for (int i = start; i < end; ++i) s += count[i];
    sums[tid] = s;
    __syncthreads();
    // Hillis-Steele inclusive scan
    for (int d = 1; d < 1024; d <<= 1) {
        int t = (tid >= d) ? sums[tid - d] : 0;
        __syncthreads();
        sums[tid] += t;
        __syncthreads();
    }
    int off = sums[tid] - s;  // exclusive prefix
    for (int i = start; i < end; ++i) {
        int c = count[i];
        row_ptr[i] = off;
        cursor[i] = off;
        dis[i] = (c > 0) ? rsqrtf((float)c) : 0.0f;
        off += c;
    }
    if (tid == 1023) row_ptr[N] = off;
}

__global__ void k_fill(const int* __restrict__ src, const int* __restrict__ dst, int E,
                       const float* __restrict__ dis, int* __restrict__ cursor,
                       int* __restrict__ csr_src, float* __restrict__ csr_norm) {
    int e = blockIdx.x * blockDim.x + threadIdx.x;
    if (e < E) {
        int s = src[e];
        int d = dst[e];
        int pos = atomicAdd(&cursor[d], 1);
        csr_src[pos] = s;
        csr_norm[pos] = -dis[s] * dis[d];
    }
}

// Tiled fp32 GEMM: C[N,FOUT] = A[N,FIN] @ W[FIN,FOUT]. W fits in LDS.
template <int FIN, int FOUT, int TM, int TN, int NT>
__global__ __launch_bounds__(NT) void k_gemm(const float* __restrict__ A,
                                             const float* __restrict__ W,
                                             float* __restrict__ C, int N) {
    constexpr int BM = 64;
    constexpr int TXN = FOUT / TN;
    __shared__ float Xs[FIN][BM + 4];  // X^T tile; +4 pad: stride 272B (16B-mult)
    __shared__ float Ws[FIN][FOUT];
    int tid = threadIdx.x;
    int row0 = blockIdx.x * BM;

    // stage X^T: Xs[k][i] = A[row0+i][k]
    for (int idx = tid; idx < FIN * BM; idx += NT) {
        int i = idx / FIN;
        int k = idx - i * FIN;
        int r = row0 + i;
        Xs[k][i] = (r < N) ? A[(size_t)r * FIN + k] : 0.0f;
    }
    // stage W
    for (int idx = tid; idx < FIN * FOUT; idx += NT) {
        Ws[idx / FOUT][idx % FOUT] = W[idx];
    }
    __syncthreads();

    int ty = tid / TXN, tx = tid % TXN;
    float acc[TM][TN];
#pragma unroll
    for (int a = 0; a < TM; ++a)
#pragma unroll
        for (int b = 0; b < TN; ++b) acc[a][b] = 0.0f;

#pragma unroll 4
    for (int k = 0; k < FIN; ++k) {
        float av[TM], bv[TN];
#pragma unroll
        for (int mi = 0; mi < TM; ++mi) av[mi] = Xs[k][ty * TM + mi];
#pragma unroll
        for (int ni = 0; ni < TN; ++ni) bv[ni] = Ws[k][tx * TN + ni];
#pragma unroll
        for (int mi = 0; mi < TM; ++mi)
#pragma unroll
            for (int ni = 0; ni < TN; ++ni)
                acc[mi][ni] = fmaf(av[mi], bv[ni], acc[mi][ni]);
    }

#pragma unroll
    for (int mi = 0; mi < TM; ++mi) {
        int r = row0 + ty * TM + mi;
        if (r < N) {
#pragma unroll
            for (int ni = 0; ni < TN; ++ni)
                C[(size_t)r * FOUT + tx * TN + ni] = acc[mi][ni];
        }
    }
}

// CSR gather-prop with fused epilogue. One 64-lane wave per dst node, lane=feature.
// MODE 0: out = o0 + 2*acc
// MODE 1: out = relu(o0 - o1 + acc + bias[f])
// MODE 2: z = o0 - o1 + acc + bias[f]; out = log_softmax(z) over F classes
template <int F, int MODE>
__global__ void k_prop(const int* __restrict__ row_ptr, const int* __restrict__ csr_src,
                       const float* __restrict__ csr_norm, const float* __restrict__ in,
                       const float* __restrict__ o0, const float* __restrict__ o1,
                       const float* __restrict__ bias, float* __restrict__ out, int N) {
    int wid = (blockIdx.x * blockDim.x + threadIdx.x) >> 6;
    int lane = threadIdx.x & 63;
    if (wid >= N) return;
    int beg = row_ptr[wid];
    int end = row_ptr[wid + 1];
    float acc = 0.0f;
    for (int j = beg; j < end; ++j) {
        int s = csr_src[j];      // wave-uniform
        float w = csr_norm[j];   // wave-uniform
        float v = (lane < F) ? in[(size_t)s * F + lane] : 0.0f;
        acc = fmaf(w, v, acc);
    }
    size_t o = (size_t)wid * F + lane;
    if (MODE == 0) {
        if (lane < F) out[o] = o0[o] + 2.0f * acc;
    } else if (MODE == 1) {
        if (lane < F) {
            float z = o0[o] - o1[o] + acc + bias[lane];
            out[o] = fmaxf(z, 0.0f);
        }
    } else {
        float z = (lane < F) ? (o0[o] - o1[o] + acc + bias[lane]) : -INFINITY;
        float m = z;
#pragma unroll
        for (int d = 32; d; d >>= 1) m = fmaxf(m, __shfl_xor(m, d));
        float e = (lane < F) ? expf(z - m) : 0.0f;
        float l = e;
#pragma unroll
        for (int d = 32; d; d >>= 1) l += __shfl_xor(l, d);
        if (lane < F) out[o] = z - m - logf(l);
    }
}

extern "C" void kernel_launch(void* const* d_in, const int* in_sizes, int n_in,
                              void* d_out, int out_size, void* d_ws, size_t ws_size,
                              hipStream_t stream) {
    const float* x = (const float*)d_in[0];
    const int* ei = (const int*)d_in[1];
    const float* W1 = (const float*)d_in[2];
    const float* b1 = (const float*)d_in[3];
    const float* W2 = (const float*)d_in[4];
    const float* b2 = (const float*)d_in[5];
    float* out = (float*)d_out;

    const int N = in_sizes[0] / FIN1;  // 100000
    const int E = in_sizes[1] / 2;     // 1600000
    const int* src = ei;
    const int* dst = ei + E;

    // workspace carve (256B aligned)
    char* p = (char*)d_ws;
    auto alloc = [&](size_t bytes) -> void* {
        void* r = (void*)p;
        p += (bytes + 255) & ~(size_t)255;
        return r;
    };
    int* count = (int*)alloc((size_t)N * 4);
    int* row_ptr = (int*)alloc((size_t)(N + 1) * 4);
    int* cursor = (int*)alloc((size_t)N * 4);
    float* dis = (float*)alloc((size_t)N * 4);
    int* csr_src = (int*)alloc((size_t)E * 4);
    float* csr_norm = (float*)alloc((size_t)E * 4);
    float* buf0 = (float*)alloc((size_t)N * HID * 4);  // c0, later d0
    float* buf1 = (float*)alloc((size_t)N * HID * 4);  // ca, later da
    float* buf2 = (float*)alloc((size_t)N * HID * 4);  // cb, later db
    float* buf3 = (float*)alloc((size_t)N * HID * 4);  // s,  later s2
    float* buf4 = (float*)alloc((size_t)N * HID * 4);  // h

    const int be = (E + 255) / 256;
    const int bn = (N + 255) / 256;
    const int bg = (N + 63) / 64;
    const int bp = (N * 64 + 255) / 256;  // one wave per node

    // ---- graph structure: degree, CSR, norm ----
    k_zero<<<bn, 256, 0, stream>>>(count, N);
    k_count<<<be, 256, 0, stream>>>(dst, E, count);
    k_scan<<<1, 1024, 0, stream>>>(count, N, row_ptr, cursor, dis);
    k_fill<<<be, 256, 0, stream>>>(src, dst, E, dis, cursor, csr_src, csr_norm);

    // ---- layer 1: x[N,128] -> h[N,64] ----
    k_gemm<FIN1, HID, 4, 4, 256><<<bg, 256, 0, stream>>>(x, W1 + 0 * FIN1 * HID, buf0, N);
    k_gemm<FIN1, HID, 4, 4, 256><<<bg, 256, 0, stream>>>(x, W1 + 1 * FIN1 * HID, buf1, N);
    k_gemm<FIN1, HID, 4, 4, 256><<<bg, 256, 0, stream>>>(x, W1 + 2 * FIN1 * HID, buf2, N);
    // s = ca + 2*P(cb)
    k_prop<HID, 0><<<bp, 256, 0, stream>>>(row_ptr, csr_src, csr_norm, buf2, buf1,
                                           nullptr, nullptr, buf3, N);
    // h = relu(c0 - cb + P(s) + b1)
    k_prop<HID, 1><<<bp, 256, 0, stream>>>(row_ptr, csr_src, csr_norm, buf3, buf0,
                                           buf2, b1, buf4, N);

    // ---- layer 2: h[N,64] -> out[N,40] ----
    k_gemm<HID, NCLS, 4, 5, 128><<<bg, 128, 0, stream>>>(buf4, W2 + 0 * HID * NCLS, buf0, N);
    k_gemm<HID, NCLS, 4, 5, 128><<<bg, 128, 0, stream>>>(buf4, W2 + 1 * HID * NCLS, buf1, N);
    k_gemm<HID, NCLS, 4, 5, 128><<<bg, 128, 0, stream>>>(buf4, W2 + 2 * HID * NCLS, buf2, N);
    // s2 = da + 2*P(db)
    k_prop<NCLS, 0><<<bp, 256, 0, stream>>>(row_ptr, csr_src, csr_norm, buf2, buf1,
                                            nullptr, nullptr, buf3, N);
    // out = log_softmax(d0 - db + P(s2) + b2)
    k_prop<NCLS, 2><<<bp, 256, 0, stream>>>(row_ptr, csr_src, csr_norm, buf3, buf0,
                                            buf2, b2, out, N);
}

// Round 2
// 1034.693 us; speedup vs baseline: 1.2606x; 1.2606x over previous
//
#include <hip/hip_runtime.h>
#include <hip/hip_bf16.h>
#include <math.h>

// ---------------------------------------------------------------------------
// ChebNet (K=3) two-layer forward, restructured:
//   cheb(x,W) = x@W0 - x@W2 + P(x@W1 + 2*P(x@W2)) + b,  P = edge scatter-sum
// P applied in output feature space (64 then 40 dims).
// Edge scatter converted to CSR-by-dst gather (hierarchical scan build).
// Per layer, the 3 weight matrices are fused into one GEMM kernel.
// ---------------------------------------------------------------------------

#define FIN1 128
#define HID 64
#define NCLS 40

__global__ void k_count(const int* __restrict__ dst, int E, int* __restrict__ count) {
    int e = blockIdx.x * blockDim.x + threadIdx.x;
    if (e < E) atomicAdd(&count[dst[e]], 1);
}

// ---- hierarchical exclusive scan over count[N] ----
template <int EPT>
__global__ __launch_bounds__(256) void k_scan_part(const int* __restrict__ count, int N,
                                                   int* __restrict__ partial) {
    __shared__ int ws[4];
    int t = threadIdx.x;
    int lane = t & 63, w = t >> 6;
    int idx0 = blockIdx.x * 256 * EPT + t * EPT;
    int s = 0;
#pragma unroll
    for (int i = 0; i < EPT; ++i) {
        int idx = idx0 + i;
        if (idx < N) s += count[idx];
    }
#pragma unroll
    for (int d = 1; d < 64; d <<= 1) s += __shfl_xor(s, d);
    if (lane == 0) ws[w] = s;
    __syncthreads();
    if (t == 0) partial[blockIdx.x] = ws[0] + ws[1] + ws[2] + ws[3];
}

__global__ __launch_bounds__(256) void k_scan_mid(int* __restrict__ partial, int nb) {
    __shared__ int s[256];
    int t = threadIdx.x;
    int orig = (t < nb) ? partial[t] : 0;
    s[t] = orig;
    __syncthreads();
    for (int d = 1; d < 256; d <<= 1) {
        int v = (t >= d) ? s[t - d] : 0;
        __syncthreads();
        s[t] += v;
        __syncthreads();
    }
    if (t < nb) partial[t] = s[t] - orig;  // exclusive
}

template <int EPT>
__global__ __launch_bounds__(256) void k_scan_final(const int* __restrict__ count, int N,
                                                    const int* __restrict__ partial,
                                                    int* __restrict__ row_ptr,
                                                    int* __restrict__ cursor,
                                                    float* __restrict__ dis) {
    __shared__ int wsum[4];
    int t = threadIdx.x;
    int lane = t & 63, w = t >> 6;
    int idx0 = blockIdx.x * 256 * EPT + t * EPT;
    int c[EPT];
    int s = 0;
#pragma unroll
    for (int i = 0; i < EPT; ++i) {
        int idx = idx0 + i;
        c[i] = (idx < N) ? count[idx] : 0;
        s += c[i];
    }
    int incl = s;
#pragma unroll
    for (int d = 1; d < 64; d <<= 1) {
        int u = __shfl_up(incl, d);
        if (lane >= d) incl += u;
    }
    if (lane == 63) wsum[w] = incl;
    __syncthreads();
    int woff = 0;
    for (int i = 0; i < w; ++i) woff += wsum[i];
    int off = partial[blockIdx.x] + woff + (incl - s);
#pragma unroll
    for (int i = 0; i < EPT; ++i) {
        int idx = idx0 + i;
        if (idx < N) {
            row_ptr[idx] = off;
            cursor[idx] = off;
            dis[idx] = (c[i] > 0) ? rsqrtf((float)c[i]) : 0.0f;
            off += c[i];
            if (idx == N - 1) row_ptr[N] = off;
        }
    }
}

__global__ void k_fill(const int* __restrict__ src, const int* __restrict__ dst, int E,
                       const float* __restrict__ dis, int* __restrict__ cursor,
                       int* __restrict__ csr_src, float* __restrict__ csr_norm) {
    int e = blockIdx.x * blockDim.x + threadIdx.x;
    if (e < E) {
        int s = src[e];
        int d = dst[e];
        int pos = atomicAdd(&cursor[d], 1);
        csr_src[pos] = s;
        csr_norm[pos] = -dis[s] * dis[d];
    }
}

// Fused 3-matrix GEMM: C{0,1,2}[N,FOE] = A[N,FIN] @ Wall[m][FIN][FOE], m=0..2.
// FO = 3*FOE fused output columns; X and W staged once in LDS.
template <int FIN, int FO, int FOE, int TM, int TN, int NT>
__global__ __launch_bounds__(NT) void k_gemm3(const float* __restrict__ A,
                                              const float* __restrict__ Wall,
                                              float* __restrict__ C0,
                                              float* __restrict__ C1,
                                              float* __restrict__ C2, int N) {
    constexpr int BM = 64;
    constexpr int TXN = FO / TN;
    constexpr int TYM = BM / TM;
    static_assert(TXN * TYM <= NT, "thread tiling mismatch");
    __shared__ float Xs[FIN][BM + 4];  // X^T tile; +4 pad keeps 16B alignment
    __shared__ float Ws[FIN][FO];
    int tid = threadIdx.x;
    int row0 = blockIdx.x * BM;

    // stage X^T: Xs[k][i] = A[row0+i][k]  (global reads coalesced along k)
    for (int idx = tid; idx < FIN * BM; idx += NT) {
        int i = idx / FIN;
        int k = idx - i * FIN;
        int r = row0 + i;
        Xs[k][i] = (r < N) ? A[(size_t)r * FIN + k] : 0.0f;
    }
    // stage W: Ws[k][m*FOE+c] = Wall[m][k][c]
    for (int idx = tid; idx < 3 * FIN * FOE; idx += NT) {
        int m = idx / (FIN * FOE);
        int rem = idx - m * (FIN * FOE);
        int k = rem / FOE;
        int c = rem - k * FOE;
        Ws[k][m * FOE + c] = Wall[idx];
    }
    __syncthreads();

    int ty = tid / TXN, tx = tid - ty * TXN;
    if (ty >= TYM) return;

    float acc[TM][TN];
#pragma unroll
    for (int a = 0; a < TM; ++a)
#pragma unroll
        for (int b = 0; b < TN; ++b) acc[a][b] = 0.0f;

#pragma unroll 4
    for (int k = 0; k < FIN; ++k) {
        float av[TM], bv[TN];
#pragma unroll
        for (int mi = 0; mi < TM; ++mi) av[mi] = Xs[k][ty * TM + mi];
#pragma unroll
        for (int ni = 0; ni < TN; ++ni) bv[ni] = Ws[k][tx * TN + ni];
#pragma unroll
        for (int mi = 0; mi < TM; ++mi)
#pragma unroll
            for (int ni = 0; ni < TN; ++ni)
                acc[mi][ni] = fmaf(av[mi], bv[ni], acc[mi][ni]);
    }

#pragma unroll
    for (int mi = 0; mi < TM; ++mi) {
        int r = row0 + ty * TM + mi;
        if (r < N) {
#pragma unroll
            for (int ni = 0; ni < TN; ++ni) {
                int col = tx * TN + ni;
                int m = col / FOE;
                int cc = col - m * FOE;
                float* Cm = (m == 0) ? C0 : ((m == 1) ? C1 : C2);
                Cm[(size_t)r * FOE + cc] = acc[mi][ni];
            }
        }
    }
}

// CSR gather-prop with fused epilogue. One 64-lane wave per dst node, lane=feature.
// MODE 0: out = o0 + 2*acc
// MODE 1: out = relu(o0 - o1 + acc + bias[f])
// MODE 2: z = o0 - o1 + acc + bias[f]; out = log_softmax(z) over F classes
template <int F, int MODE>
__global__ void k_prop(const int* __restrict__ row_ptr, const int* __restrict__ csr_src,
                       const float* __restrict__ csr_norm, const float* __restrict__ in,
                       const float* __restrict__ o0, const float* __restrict__ o1,
                       const float* __restrict__ bias, float* __restrict__ out, int N) {
    int wid = (blockIdx.x * blockDim.x + threadIdx.x) >> 6;
    int lane = threadIdx.x & 63;
    if (wid >= N) return;
    int beg = row_ptr[wid];
    int end = row_ptr[wid + 1];
    float acc = 0.0f;
    for (int j = beg; j < end; ++j) {
        int s = csr_src[j];      // wave-uniform
        float w = csr_norm[j];   // wave-uniform
        float v = (lane < F) ? in[(size_t)s * F + lane] : 0.0f;
        acc = fmaf(w, v, acc);
    }
    size_t o = (size_t)wid * F + lane;
    if (MODE == 0) {
        if (lane < F) out[o] = o0[o] + 2.0f * acc;
    } else if (MODE == 1) {
        if (lane < F) {
            float z = o0[o] - o1[o] + acc + bias[lane];
            out[o] = fmaxf(z, 0.0f);
        }
    } else {
        float z = (lane < F) ? (o0[o] - o1[o] + acc + bias[lane]) : -INFINITY;
        float m = z;
#pragma unroll
        for (int d = 32; d; d >>= 1) m = fmaxf(m, __shfl_xor(m, d));
        float e = (lane < F) ? expf(z - m) : 0.0f;
        float l = e;
#pragma unroll
        for (int d = 32; d; d >>= 1) l += __shfl_xor(l, d);
        if (lane < F) out[o] = z - m - logf(l);
    }
}

extern "C" void kernel_launch(void* const* d_in, const int* in_sizes, int n_in,
                              void* d_out, int out_size, void* d_ws, size_t ws_size,
                              hipStream_t stream) {
    const float* x = (const float*)d_in[0];
    const int* ei = (const int*)d_in[1];
    const float* W1 = (const float*)d_in[2];
    const float* b1 = (const float*)d_in[3];
    const float* W2 = (const float*)d_in[4];
    const float* b2 = (const float*)d_in[5];
    float* out = (float*)d_out;

    const int N = in_sizes[0] / FIN1;  // 100000
    const int E = in_sizes[1] / 2;     // 1600000
    const int* src = ei;
    const int* dst = ei + E;

    // workspace carve (256B aligned)
    char* p = (char*)d_ws;
    auto alloc = [&](size_t bytes) -> void* {
        void* r = (void*)p;
        p += (bytes + 255) & ~(size_t)255;
        return r;
    };
    int* count = (int*)alloc((size_t)N * 4);
    int* row_ptr = (int*)alloc((size_t)(N + 1) * 4);
    int* cursor = (int*)alloc((size_t)N * 4);
    float* dis = (float*)alloc((size_t)N * 4);
    int* partial = (int*)alloc(256 * 4);
    int* csr_src = (int*)alloc((size_t)E * 4);
    float* csr_norm = (float*)alloc((size_t)E * 4);
    float* buf0 = (float*)alloc((size_t)N * HID * 4);  // c0, later d0
    float* buf1 = (float*)alloc((size_t)N * HID * 4);  // ca, later da
    float* buf2 = (float*)alloc((size_t)N * HID * 4);  // cb, later db
    float* buf3 = (float*)alloc((size_t)N * HID * 4);  // s,  later s2
    float* buf4 = (float*)alloc((size_t)N * HID * 4);  // h

    const int be = (E + 255) / 256;
    const int bg = (N + 63) / 64;
    const int bp = (N * 64 + 255) / 256;  // one wave per node
    constexpr int EPB = 256 * 8;
    const int nb = (N + EPB - 1) / EPB;   // 49 blocks for N=100000

    // ---- graph structure: degree, CSR, norm ----
    hipMemsetAsync(count, 0, (size_t)N * 4, stream);
    k_count<<<be, 256, 0, stream>>>(dst, E, count);
    k_scan_part<8><<<nb, 256, 0, stream>>>(count, N, partial);
    k_scan_mid<<<1, 256, 0, stream>>>(partial, nb);
    k_scan_final<8><<<nb, 256, 0, stream>>>(count, N, partial, row_ptr, cursor, dis);
    k_fill<<<be, 256, 0, stream>>>(src, dst, E, dis, cursor, csr_src, csr_norm);

    // ---- layer 1: x[N,128] -> h[N,64] ----
    k_gemm3<FIN1, 192, HID, 4, 12, 256><<<bg, 256, 0, stream>>>(x, W1, buf0, buf1, buf2, N);
    // s = ca + 2*P(cb)
    k_prop<HID, 0><<<bp, 256, 0, stream>>>(row_ptr, csr_src, csr_norm, buf2, buf1,
                                           nullptr, nullptr, buf3, N);
    // h = relu(c0 - cb + P(s) + b1)
    k_prop<HID, 1><<<bp, 256, 0, stream>>>(row_ptr, csr_src, csr_norm, buf3, buf0,
                                           buf2, b1, buf4, N);

    // ---- layer 2: h[N,64] -> out[N,40] ----
    k_gemm3<HID, 120, NCLS, 4, 8, 256><<<bg, 256, 0, stream>>>(buf4, W2, buf0, buf1, buf2, N);
    // s2 = da + 2*P(db)
    k_prop<NCLS, 0><<<bp, 256, 0, stream>>>(row_ptr, csr_src, csr_norm, buf2, buf1,
                                            nullptr, nullptr, buf3, N);
    // out = log_softmax(d0 - db + P(s2) + b2)
    k_prop<NCLS, 2><<<bp, 256, 0, stream>>>(row_ptr, csr_src, csr_norm, buf3, buf0,
                                            buf2, b2, out, N);
}

// Round 3
// 767.172 us; speedup vs baseline: 1.7002x; 1.3487x over previous
//
#include <hip/hip_runtime.h>
#include <hip/hip_bf16.h>
#include <math.h>

// ---------------------------------------------------------------------------
// ChebNet (K=3) two-layer forward, restructured:
//   cheb(x,W) = x@W0 - x@W2 + P(x@W1 + 2*P(x@W2)) + b,  P = edge scatter-sum
// P applied in output feature space (64 then 40 dims).
// Edge scatter converted to CSR-by-dst gather (hierarchical scan build).
// Per layer, the 3 weight matrices are fused into one GEMM kernel.
// GEMM stages K in chunks of 32 so LDS/block = 33 KB -> 4 blocks/CU.
// ---------------------------------------------------------------------------

#define FIN1 128
#define HID 64
#define NCLS 40

__global__ void k_count(const int* __restrict__ dst, int E, int* __restrict__ count) {
    int e = blockIdx.x * blockDim.x + threadIdx.x;
    if (e < E) atomicAdd(&count[dst[e]], 1);
}

// ---- hierarchical exclusive scan over count[N] ----
template <int EPT>
__global__ __launch_bounds__(256) void k_scan_part(const int* __restrict__ count, int N,
                                                   int* __restrict__ partial) {
    __shared__ int ws[4];
    int t = threadIdx.x;
    int lane = t & 63, w = t >> 6;
    int idx0 = blockIdx.x * 256 * EPT + t * EPT;
    int s = 0;
#pragma unroll
    for (int i = 0; i < EPT; ++i) {
        int idx = idx0 + i;
        if (idx < N) s += count[idx];
    }
#pragma unroll
    for (int d = 1; d < 64; d <<= 1) s += __shfl_xor(s, d);
    if (lane == 0) ws[w] = s;
    __syncthreads();
    if (t == 0) partial[blockIdx.x] = ws[0] + ws[1] + ws[2] + ws[3];
}

__global__ __launch_bounds__(256) void k_scan_mid(int* __restrict__ partial, int nb) {
    __shared__ int s[256];
    int t = threadIdx.x;
    int orig = (t < nb) ? partial[t] : 0;
    s[t] = orig;
    __syncthreads();
    for (int d = 1; d < 256; d <<= 1) {
        int v = (t >= d) ? s[t - d] : 0;
        __syncthreads();
        s[t] += v;
        __syncthreads();
    }
    if (t < nb) partial[t] = s[t] - orig;  // exclusive
}

template <int EPT>
__global__ __launch_bounds__(256) void k_scan_final(const int* __restrict__ count, int N,
                                                    const int* __restrict__ partial,
                                                    int* __restrict__ row_ptr,
                                                    int* __restrict__ cursor,
                                                    float* __restrict__ dis) {
    __shared__ int wsum[4];
    int t = threadIdx.x;
    int lane = t & 63, w = t >> 6;
    int idx0 = blockIdx.x * 256 * EPT + t * EPT;
    int c[EPT];
    int s = 0;
#pragma unroll
    for (int i = 0; i < EPT; ++i) {
        int idx = idx0 + i;
        c[i] = (idx < N) ? count[idx] : 0;
        s += c[i];
    }
    int incl = s;
#pragma unroll
    for (int d = 1; d < 64; d <<= 1) {
        int u = __shfl_up(incl, d);
        if (lane >= d) incl += u;
    }
    if (lane == 63) wsum[w] = incl;
    __syncthreads();
    int woff = 0;
    for (int i = 0; i < w; ++i) woff += wsum[i];
    int off = partial[blockIdx.x] + woff + (incl - s);
#pragma unroll
    for (int i = 0; i < EPT; ++i) {
        int idx = idx0 + i;
        if (idx < N) {
            row_ptr[idx] = off;
            cursor[idx] = off;
            dis[idx] = (c[i] > 0) ? rsqrtf((float)c[i]) : 0.0f;
            off += c[i];
            if (idx == N - 1) row_ptr[N] = off;
        }
    }
}

__global__ void k_fill(const int* __restrict__ src, const int* __restrict__ dst, int E,
                       const float* __restrict__ dis, int* __restrict__ cursor,
                       int* __restrict__ csr_src, float* __restrict__ csr_norm) {
    int e = blockIdx.x * blockDim.x + threadIdx.x;
    if (e < E) {
        int s = src[e];
        int d = dst[e];
        int pos = atomicAdd(&cursor[d], 1);
        csr_src[pos] = s;
        csr_norm[pos] = -dis[s] * dis[d];
    }
}

// Fused 3-matrix GEMM: C{0,1,2}[N,FOE] = A[N,FIN] @ Wall[m][FIN][FOE], m=0..2.
// FO = 3*FOE fused output columns. K staged in chunks of KQ -> small LDS.
template <int FIN, int FO, int FOE, int TM, int TN, int NT, int KQ>
__global__ __launch_bounds__(NT, 4) void k_gemm3(const float* __restrict__ A,
                                                 const float* __restrict__ Wall,
                                                 float* __restrict__ C0,
                                                 float* __restrict__ C1,
                                                 float* __restrict__ C2, int N) {
    constexpr int BM = 64;
    constexpr int TXN = FO / TN;
    constexpr int TYM = BM / TM;
    static_assert(TXN * TYM <= NT, "thread tiling mismatch");
    __shared__ float Xs[KQ][BM + 4];  // X^T chunk; +4 pad keeps 16B alignment
    __shared__ float Ws[KQ][FO];
    int tid = threadIdx.x;
    int row0 = blockIdx.x * BM;

    int ty = tid / TXN, tx = tid - ty * TXN;
    bool active = (ty < TYM);

    float acc[TM][TN];
#pragma unroll
    for (int a = 0; a < TM; ++a)
#pragma unroll
        for (int b = 0; b < TN; ++b) acc[a][b] = 0.0f;

    for (int kq = 0; kq < FIN; kq += KQ) {
        __syncthreads();  // previous chunk fully consumed
        // stage X^T chunk: Xs[kk][i] = A[row0+i][kq+kk]
        for (int idx = tid; idx < KQ * BM; idx += NT) {
            int i = idx / KQ;
            int kk = idx - i * KQ;
            int r = row0 + i;
            Xs[kk][i] = (r < N) ? A[(size_t)r * FIN + kq + kk] : 0.0f;
        }
        // stage W chunk: Ws[kk][m*FOE+c] = Wall[m][kq+kk][c]
        for (int idx = tid; idx < 3 * KQ * FOE; idx += NT) {
            int m = idx / (KQ * FOE);
            int rem = idx - m * (KQ * FOE);
            int kk = rem / FOE;
            int c = rem - kk * FOE;
            Ws[kk][m * FOE + c] = Wall[m * FIN * FOE + (kq + kk) * FOE + c];
        }
        __syncthreads();

        if (active) {
#pragma unroll 4
            for (int kk = 0; kk < KQ; ++kk) {
                float av[TM], bv[TN];
#pragma unroll
                for (int mi = 0; mi < TM; ++mi) av[mi] = Xs[kk][ty * TM + mi];
#pragma unroll
                for (int ni = 0; ni < TN; ++ni) bv[ni] = Ws[kk][tx * TN + ni];
#pragma unroll
                for (int mi = 0; mi < TM; ++mi)
#pragma unroll
                    for (int ni = 0; ni < TN; ++ni)
                        acc[mi][ni] = fmaf(av[mi], bv[ni], acc[mi][ni]);
            }
        }
    }

    if (active) {
#pragma unroll
        for (int mi = 0; mi < TM; ++mi) {
            int r = row0 + ty * TM + mi;
            if (r < N) {
#pragma unroll
                for (int ni = 0; ni < TN; ++ni) {
                    int col = tx * TN + ni;
                    int m = col / FOE;
                    int cc = col - m * FOE;
                    float* Cm = (m == 0) ? C0 : ((m == 1) ? C1 : C2);
                    Cm[(size_t)r * FOE + cc] = acc[mi][ni];
                }
            }
        }
    }
}

// CSR gather-prop with fused epilogue. One 64-lane wave per dst node, lane=feature.
// Edge metadata loaded coalesced in 64-wide chunks, broadcast via shfl.
// MODE 0: out = o0 + 2*acc
// MODE 1: out = relu(o0 - o1 + acc + bias[f])
// MODE 2: z = o0 - o1 + acc + bias[f]; out = log_softmax(z) over F classes
template <int F, int MODE>
__global__ void k_prop(const int* __restrict__ row_ptr, const int* __restrict__ csr_src,
                       const float* __restrict__ csr_norm, const float* __restrict__ in,
                       const float* __restrict__ o0, const float* __restrict__ o1,
                       const float* __restrict__ bias, float* __restrict__ out, int N) {
    int wid = (blockIdx.x * blockDim.x + threadIdx.x) >> 6;
    int lane = threadIdx.x & 63;
    if (wid >= N) return;
    int beg = row_ptr[wid];
    int end = row_ptr[wid + 1];
    float acc = 0.0f;
    for (int j0 = beg; j0 < end; j0 += 64) {
        int navail = end - j0;
        int jj = j0 + lane;
        int s_l = (lane < navail) ? csr_src[jj] : 0;
        float w_l = (lane < navail) ? csr_norm[jj] : 0.0f;
        int cnt = min(navail, 64);
        for (int t = 0; t < cnt; ++t) {
            int s = __shfl(s_l, t);
            float w = __shfl(w_l, t);
            float v = (lane < F) ? in[(size_t)s * F + lane] : 0.0f;
            acc = fmaf(w, v, acc);
        }
    }
    size_t o = (size_t)wid * F + lane;
    if (MODE == 0) {
        if (lane < F) out[o] = o0[o] + 2.0f * acc;
    } else if (MODE == 1) {
        if (lane < F) {
            float z = o0[o] - o1[o] + acc + bias[lane];
            out[o] = fmaxf(z, 0.0f);
        }
    } else {
        float z = (lane < F) ? (o0[o] - o1[o] + acc + bias[lane]) : -INFINITY;
        float m = z;
#pragma unroll
        for (int d = 32; d; d >>= 1) m = fmaxf(m, __shfl_xor(m, d));
        float e = (lane < F) ? expf(z - m) : 0.0f;
        float l = e;
#pragma unroll
        for (int d = 32; d; d >>= 1) l += __shfl_xor(l, d);
        if (lane < F) out[o] = z - m - logf(l);
    }
}

extern "C" void kernel_launch(void* const* d_in, const int* in_sizes, int n_in,
                              void* d_out, int out_size, void* d_ws, size_t ws_size,
                              hipStream_t stream) {
    const float* x = (const float*)d_in[0];
    const int* ei = (const int*)d_in[1];
    const float* W1 = (const float*)d_in[2];
    const float* b1 = (const float*)d_in[3];
    const float* W2 = (const float*)d_in[4];
    const float* b2 = (const float*)d_in[5];
    float* out = (float*)d_out;

    const int N = in_sizes[0] / FIN1;  // 100000
    const int E = in_sizes[1] / 2;     // 1600000
    const int* src = ei;
    const int* dst = ei + E;

    // workspace carve (256B aligned)
    char* p = (char*)d_ws;
    auto alloc = [&](size_t bytes) -> void* {
        void* r = (void*)p;
        p += (bytes + 255) & ~(size_t)255;
        return r;
    };
    int* count = (int*)alloc((size_t)N * 4);
    int* row_ptr = (int*)alloc((size_t)(N + 1) * 4);
    int* cursor = (int*)alloc((size_t)N * 4);
    float* dis = (float*)alloc((size_t)N * 4);
    int* partial = (int*)alloc(256 * 4);
    int* csr_src = (int*)alloc((size_t)E * 4);
    float* csr_norm = (float*)alloc((size_t)E * 4);
    float* buf0 = (float*)alloc((size_t)N * HID * 4);  // c0, later d0
    float* buf1 = (float*)alloc((size_t)N * HID * 4);  // ca, later da
    float* buf2 = (float*)alloc((size_t)N * HID * 4);  // cb, later db
    float* buf3 = (float*)alloc((size_t)N * HID * 4);  // s,  later s2
    float* buf4 = (float*)alloc((size_t)N * HID * 4);  // h

    const int be = (E + 255) / 256;
    const int bg = (N + 63) / 64;
    const int bp = (N * 64 + 255) / 256;  // one wave per node
    constexpr int EPB = 256 * 8;
    const int nb = (N + EPB - 1) / EPB;   // 49 blocks for N=100000

    // ---- graph structure: degree, CSR, norm ----
    hipMemsetAsync(count, 0, (size_t)N * 4, stream);
    k_count<<<be, 256, 0, stream>>>(dst, E, count);
    k_scan_part<8><<<nb, 256, 0, stream>>>(count, N, partial);
    k_scan_mid<<<1, 256, 0, stream>>>(partial, nb);
    k_scan_final<8><<<nb, 256, 0, stream>>>(count, N, partial, row_ptr, cursor, dis);
    k_fill<<<be, 256, 0, stream>>>(src, dst, E, dis, cursor, csr_src, csr_norm);

    // ---- layer 1: x[N,128] -> h[N,64] ----
    k_gemm3<FIN1, 192, HID, 4, 12, 256, 32><<<bg, 256, 0, stream>>>(x, W1, buf0, buf1, buf2, N);
    // s = ca + 2*P(cb)
    k_prop<HID, 0><<<bp, 256, 0, stream>>>(row_ptr, csr_src, csr_norm, buf2, buf1,
                                           nullptr, nullptr, buf3, N);
    // h = relu(c0 - cb + P(s) + b1)
    k_prop<HID, 1><<<bp, 256, 0, stream>>>(row_ptr, csr_src, csr_norm, buf3, buf0,
                                           buf2, b1, buf4, N);

    // ---- layer 2: h[N,64] -> out[N,40] ----
    k_gemm3<HID, 120, NCLS, 4, 8, 256, 32><<<bg, 256, 0, stream>>>(buf4, W2, buf0, buf1, buf2, N);
    // s2 = da + 2*P(db)
    k_prop<NCLS, 0><<<bp, 256, 0, stream>>>(row_ptr, csr_src, csr_norm, buf2, buf1,
                                            nullptr, nullptr, buf3, N);
    // out = log_softmax(d0 - db + P(s2) + b2)
    k_prop<NCLS, 2><<<bp, 256, 0, stream>>>(row_ptr, csr_src, csr_norm, buf3, buf0,
                                            buf2, b2, out, N);
}

// Round 4
// 648.735 us; speedup vs baseline: 2.0107x; 1.1826x over previous
//
#include <hip/hip_runtime.h>
#include <hip/hip_bf16.h>
#include <math.h>

// ---------------------------------------------------------------------------
// ChebNet (K=3) two-layer forward, restructured:
//   cheb(x,W) = x@W0 - x@W2 + P(x@W1 + 2*P(x@W2)) + b,  P = edge scatter-sum
// P applied in output feature space (64 then 40 dims).
// Edge scatter converted to CSR-by-dst gather (hierarchical scan build).
// GEMMs: bf16 MFMA (16x16x32) with hi/lo split (fp32-accurate):
//   A@W ~= Ahi@Whi + Ahi@Wlo + Alo@Whi   (error ~ Alo@Wlo ~ 1e-5 relative)
// W pre-swizzled into B-fragment layout once per launch; A frags read straight
// from global (no LDS anywhere in the GEMM).
// ---------------------------------------------------------------------------

#define FIN1 128
#define HID 64
#define NCLS 40

typedef __attribute__((ext_vector_type(8))) short sx8;
typedef __attribute__((ext_vector_type(4))) float fx4;

__device__ inline unsigned short f2bf(float f) {
    unsigned u = __float_as_uint(f);
    unsigned r = (u + 0x7FFF + ((u >> 16) & 1)) >> 16;  // RNE
    return (unsigned short)r;
}
__device__ inline float bf2f(unsigned short h) {
    return __uint_as_float((unsigned)h << 16);
}

__global__ void k_count(const int* __restrict__ dst, int E, int* __restrict__ count) {
    int e = blockIdx.x * blockDim.x + threadIdx.x;
    if (e < E) atomicAdd(&count[dst[e]], 1);
}

// ---- hierarchical exclusive scan over count[N] ----
template <int EPT>
__global__ __launch_bounds__(256) void k_scan_part(const int* __restrict__ count, int N,
                                                   int* __restrict__ partial) {
    __shared__ int ws[4];
    int t = threadIdx.x;
    int lane = t & 63, w = t >> 6;
    int idx0 = blockIdx.x * 256 * EPT + t * EPT;
    int s = 0;
#pragma unroll
    for (int i = 0; i < EPT; ++i) {
        int idx = idx0 + i;
        if (idx < N) s += count[idx];
    }
#pragma unroll
    for (int d = 1; d < 64; d <<= 1) s += __shfl_xor(s, d);
    if (lane == 0) ws[w] = s;
    __syncthreads();
    if (t == 0) partial[blockIdx.x] = ws[0] + ws[1] + ws[2] + ws[3];
}

__global__ __launch_bounds__(256) void k_scan_mid(int* __restrict__ partial, int nb) {
    __shared__ int s[256];
    int t = threadIdx.x;
    int orig = (t < nb) ? partial[t] : 0;
    s[t] = orig;
    __syncthreads();
    for (int d = 1; d < 256; d <<= 1) {
        int v = (t >= d) ? s[t - d] : 0;
        __syncthreads();
        s[t] += v;
        __syncthreads();
    }
    if (t < nb) partial[t] = s[t] - orig;  // exclusive
}

template <int EPT>
__global__ __launch_bounds__(256) void k_scan_final(const int* __restrict__ count, int N,
                                                    const int* __restrict__ partial,
                                                    int* __restrict__ row_ptr,
                                                    int* __restrict__ cursor,
                                                    float* __restrict__ dis) {
    __shared__ int wsum[4];
    int t = threadIdx.x;
    int lane = t & 63, w = t >> 6;
    int idx0 = blockIdx.x * 256 * EPT + t * EPT;
    int c[EPT];
    int s = 0;
#pragma unroll
    for (int i = 0; i < EPT; ++i) {
        int idx = idx0 + i;
        c[i] = (idx < N) ? count[idx] : 0;
        s += c[i];
    }
    int incl = s;
#pragma unroll
    for (int d = 1; d < 64; d <<= 1) {
        int u = __shfl_up(incl, d);
        if (lane >= d) incl += u;
    }
    if (lane == 63) wsum[w] = incl;
    __syncthreads();
    int woff = 0;
    for (int i = 0; i < w; ++i) woff += wsum[i];
    int off = partial[blockIdx.x] + woff + (incl - s);
#pragma unroll
    for (int i = 0; i < EPT; ++i) {
        int idx = idx0 + i;
        if (idx < N) {
            row_ptr[idx] = off;
            cursor[idx] = off;
            dis[idx] = (c[i] > 0) ? rsqrtf((float)c[i]) : 0.0f;
            off += c[i];
            if (idx == N - 1) row_ptr[N] = off;
        }
    }
}

__global__ void k_fill(const int* __restrict__ src, const int* __restrict__ dst, int E,
                       const float* __restrict__ dis, int* __restrict__ cursor,
                       int* __restrict__ csr_src, float* __restrict__ csr_norm) {
    int e = blockIdx.x * blockDim.x + threadIdx.x;
    if (e < E) {
        int s = src[e];
        int d = dst[e];
        int pos = atomicAdd(&cursor[d], 1);
        csr_src[pos] = s;
        csr_norm[pos] = -dis[s] * dis[d];
    }
}

// Pre-swizzle W[3][FIN][FOE] (fp32) into MFMA B-fragment layout, hi/lo bf16:
//   frag[s][t][lane][i] = W[m][k][c],  k = s*32 + (lane>>4)*8 + i,
//   col = t*16 + (lane&15), m = col/FOE, c = col%FOE  (zero if col >= 3*FOE)
template <int NS, int T, int FIN, int FOE>
__global__ void k_wprep(const float* __restrict__ W, unsigned short* __restrict__ hi,
                        unsigned short* __restrict__ lo) {
    int idx = blockIdx.x * 256 + threadIdx.x;
    constexpr int total = NS * T * 64 * 8;
    if (idx >= total) return;
    int i = idx & 7;
    int l = (idx >> 3) & 63;
    int t = (idx >> 9) % T;
    int s = idx / (512 * T);
    int k = s * 32 + (l >> 4) * 8 + i;
    int col = t * 16 + (l & 15);
    float w = 0.0f;
    if (col < 3 * FOE) {
        int m = col / FOE;
        int c = col - m * FOE;
        w = W[((size_t)m * FIN + k) * FOE + c];
    }
    unsigned short h = f2bf(w);
    hi[idx] = h;
    lo[idx] = f2bf(w - bf2f(h));
}

// MFMA GEMM: C{0,1,2}[N,FOE] = A[N,FIN] @ W[m][FIN][FOE] (via pre-swizzled frags).
// Block = 256 threads = 4 waves; wave w owns rows [blk*128 + w*32, +32) as 2
// row-tiles of 16; T col-tiles of 16 cover FO = 3*FOE (padded to T*16).
template <int FIN, int T, int NS, int FOE>
__global__ __launch_bounds__(256, 3) void k_gemm_mfma(
    const float* __restrict__ A, const unsigned short* __restrict__ Whi,
    const unsigned short* __restrict__ Wlo, float* __restrict__ C0,
    float* __restrict__ C1, float* __restrict__ C2, int N) {
    int tid = threadIdx.x;
    int w = tid >> 6, l = tid & 63;
    int row0 = blockIdx.x * 128 + w * 32;
    int rl = l & 15, kg = l >> 4;

    fx4 acc[2][T];
#pragma unroll
    for (int rt = 0; rt < 2; ++rt)
#pragma unroll
        for (int t = 0; t < T; ++t) acc[rt][t] = (fx4)0.0f;

    for (int s = 0; s < NS; ++s) {
        int k0 = s * 32 + kg * 8;
        sx8 ahi[2], alo[2];
#pragma unroll
        for (int rt = 0; rt < 2; ++rt) {
            int r = min(row0 + rt * 16 + rl, N - 1);
            const fx4* ap = (const fx4*)(A + (size_t)r * FIN + k0);
            fx4 a0 = ap[0];
            fx4 a1 = ap[1];
#pragma unroll
            for (int j = 0; j < 4; ++j) {
                unsigned short h0 = f2bf(a0[j]);
                unsigned short h1 = f2bf(a1[j]);
                ahi[rt][j] = (short)h0;
                ahi[rt][j + 4] = (short)h1;
                alo[rt][j] = (short)f2bf(a0[j] - bf2f(h0));
                alo[rt][j + 4] = (short)f2bf(a1[j] - bf2f(h1));
            }
        }
        const sx8* wh = (const sx8*)(Whi + ((size_t)(s * T) * 64 + l) * 8);
        const sx8* wl = (const sx8*)(Wlo + ((size_t)(s * T) * 64 + l) * 8);
#pragma unroll
        for (int t = 0; t < T; ++t) {
            sx8 bh = wh[t * 64];
            sx8 bl = wl[t * 64];
#pragma unroll
            for (int rt = 0; rt < 2; ++rt) {
                acc[rt][t] = __builtin_amdgcn_mfma_f32_16x16x32_bf16(ahi[rt], bh, acc[rt][t], 0, 0, 0);
                acc[rt][t] = __builtin_amdgcn_mfma_f32_16x16x32_bf16(ahi[rt], bl, acc[rt][t], 0, 0, 0);
                acc[rt][t] = __builtin_amdgcn_mfma_f32_16x16x32_bf16(alo[rt], bh, acc[rt][t], 0, 0, 0);
            }
        }
    }

#pragma unroll
    for (int rt = 0; rt < 2; ++rt)
#pragma unroll
        for (int t = 0; t < T; ++t) {
            int col = t * 16 + rl;
            int m = col / FOE;
            int cc = col - m * FOE;
            if (m < 3) {
                float* Cm = (m == 0) ? C0 : ((m == 1) ? C1 : C2);
#pragma unroll
                for (int j = 0; j < 4; ++j) {
                    int r = row0 + rt * 16 + kg * 4 + j;
                    if (r < N) Cm[(size_t)r * FOE + cc] = acc[rt][t][j];
                }
            }
        }
}

// CSR gather-prop with fused epilogue. One 64-lane wave per dst node, lane=feature.
// Edge metadata loaded coalesced in 64-wide chunks, broadcast via shfl.
// MODE 0: out = o0 + 2*acc
// MODE 1: out = relu(o0 - o1 + acc + bias[f])
// MODE 2: z = o0 - o1 + acc + bias[f]; out = log_softmax(z) over F classes
template <int F, int MODE>
__global__ void k_prop(const int* __restrict__ row_ptr, const int* __restrict__ csr_src,
                       const float* __restrict__ csr_norm, const float* __restrict__ in,
                       const float* __restrict__ o0, const float* __restrict__ o1,
                       const float* __restrict__ bias, float* __restrict__ out, int N) {
    int wid = (blockIdx.x * blockDim.x + threadIdx.x) >> 6;
    int lane = threadIdx.x & 63;
    if (wid >= N) return;
    int beg = row_ptr[wid];
    int end = row_ptr[wid + 1];
    float acc = 0.0f;
    for (int j0 = beg; j0 < end; j0 += 64) {
        int navail = end - j0;
        int jj = j0 + lane;
        int s_l = (lane < navail) ? csr_src[jj] : 0;
        float w_l = (lane < navail) ? csr_norm[jj] : 0.0f;
        int cnt = min(navail, 64);
        for (int t = 0; t < cnt; ++t) {
            int s = __shfl(s_l, t);
            float w = __shfl(w_l, t);
            float v = (lane < F) ? in[(size_t)s * F + lane] : 0.0f;
            acc = fmaf(w, v, acc);
        }
    }
    size_t o = (size_t)wid * F + lane;
    if (MODE == 0) {
        if (lane < F) out[o] = o0[o] + 2.0f * acc;
    } else if (MODE == 1) {
        if (lane < F) {
            float z = o0[o] - o1[o] + acc + bias[lane];
            out[o] = fmaxf(z, 0.0f);
        }
    } else {
        float z = (lane < F) ? (o0[o] - o1[o] + acc + bias[lane]) : -INFINITY;
        float m = z;
#pragma unroll
        for (int d = 32; d; d >>= 1) m = fmaxf(m, __shfl_xor(m, d));
        float e = (lane < F) ? expf(z - m) : 0.0f;
        float l = e;
#pragma unroll
        for (int d = 32; d; d >>= 1) l += __shfl_xor(l, d);
        if (lane < F) out[o] = z - m - logf(l);
    }
}

extern "C" void kernel_launch(void* const* d_in, const int* in_sizes, int n_in,
                              void* d_out, int out_size, void* d_ws, size_t ws_size,
                              hipStream_t stream) {
    const float* x = (const float*)d_in[0];
    const int* ei = (const int*)d_in[1];
    const float* W1 = (const float*)d_in[2];
    const float* b1 = (const float*)d_in[3];
    const float* W2 = (const float*)d_in[4];
    const float* b2 = (const float*)d_in[5];
    float* out = (float*)d_out;

    const int N = in_sizes[0] / FIN1;  // 100000
    const int E = in_sizes[1] / 2;     // 1600000
    const int* src = ei;
    const int* dst = ei + E;

    // workspace carve (256B aligned)
    char* p = (char*)d_ws;
    auto alloc = [&](size_t bytes) -> void* {
        void* r = (void*)p;
        p += (bytes + 255) & ~(size_t)255;
        return r;
    };
    int* count = (int*)alloc((size_t)N * 4);
    int* row_ptr = (int*)alloc((size_t)(N + 1) * 4);
    int* cursor = (int*)alloc((size_t)N * 4);
    float* dis = (float*)alloc((size_t)N * 4);
    int* partial = (int*)alloc(256 * 4);
    int* csr_src = (int*)alloc((size_t)E * 4);
    float* csr_norm = (float*)alloc((size_t)E * 4);
    float* buf0 = (float*)alloc((size_t)N * HID * 4);  // c0, later d0
    float* buf1 = (float*)alloc((size_t)N * HID * 4);  // ca, later da
    float* buf2 = (float*)alloc((size_t)N * HID * 4);  // cb, later db
    float* buf3 = (float*)alloc((size_t)N * HID * 4);  // s,  later s2
    float* buf4 = (float*)alloc((size_t)N * HID * 4);  // h
    // W fragment buffers (hi/lo bf16, B-frag layout)
    constexpr int W1FRAG = 4 * 12 * 64 * 8;  // 24576
    constexpr int W2FRAG = 2 * 8 * 64 * 8;   // 8192
    unsigned short* wf1h = (unsigned short*)alloc((size_t)W1FRAG * 2);
    unsigned short* wf1l = (unsigned short*)alloc((size_t)W1FRAG * 2);
    unsigned short* wf2h = (unsigned short*)alloc((size_t)W2FRAG * 2);
    unsigned short* wf2l = (unsigned short*)alloc((size_t)W2FRAG * 2);

    const int be = (E + 255) / 256;
    const int bg = (N + 127) / 128;       // MFMA gemm blocks (BM=128)
    const int bp = (N * 64 + 255) / 256;  // one wave per node
    constexpr int EPB = 256 * 8;
    const int nb = (N + EPB - 1) / EPB;   // 49 blocks for N=100000

    // ---- W fragment prep (independent of graph) ----
    k_wprep<4, 12, FIN1, HID><<<(W1FRAG + 255) / 256, 256, 0, stream>>>(W1, wf1h, wf1l);
    k_wprep<2, 8, HID, NCLS><<<(W2FRAG + 255) / 256, 256, 0, stream>>>(W2, wf2h, wf2l);

    // ---- graph structure: degree, CSR, norm ----
    hipMemsetAsync(count, 0, (size_t)N * 4, stream);
    k_count<<<be, 256, 0, stream>>>(dst, E, count);
    k_scan_part<8><<<nb, 256, 0, stream>>>(count, N, partial);
    k_scan_mid<<<1, 256, 0, stream>>>(partial, nb);
    k_scan_final<8><<<nb, 256, 0, stream>>>(count, N, partial, row_ptr, cursor, dis);
    k_fill<<<be, 256, 0, stream>>>(src, dst, E, dis, cursor, csr_src, csr_norm);

    // ---- layer 1: x[N,128] -> h[N,64] ----
    k_gemm_mfma<FIN1, 12, 4, HID><<<bg, 256, 0, stream>>>(x, wf1h, wf1l, buf0, buf1, buf2, N);
    // s = ca + 2*P(cb)
    k_prop<HID, 0><<<bp, 256, 0, stream>>>(row_ptr, csr_src, csr_norm, buf2, buf1,
                                           nullptr, nullptr, buf3, N);
    // h = relu(c0 - cb + P(s) + b1)
    k_prop<HID, 1><<<bp, 256, 0, stream>>>(row_ptr, csr_src, csr_norm, buf3, buf0,
                                           buf2, b1, buf4, N);

    // ---- layer 2: h[N,64] -> out[N,40] ----
    k_gemm_mfma<HID, 8, 2, NCLS><<<bg, 256, 0, stream>>>(buf4, wf2h, wf2l, buf0, buf1, buf2, N);
    // s2 = da + 2*P(db)
    k_prop<NCLS, 0><<<bp, 256, 0, stream>>>(row_ptr, csr_src, csr_norm, buf2, buf1,
                                            nullptr, nullptr, buf3, N);
    // out = log_softmax(d0 - db + P(s2) + b2)
    k_prop<NCLS, 2><<<bp, 256, 0, stream>>>(row_ptr, csr_src, csr_norm, buf3, buf0,
                                            buf2, b2, out, N);
}

// Round 5
// 533.356 us; speedup vs baseline: 2.4456x; 1.2163x over previous
//
#include <hip/hip_runtime.h>
#include <hip/hip_bf16.h>
#include <math.h>

// ---------------------------------------------------------------------------
// ChebNet (K=3) two-layer forward, restructured:
//   cheb(x,W) = x@W0 - x@W2 + P(x@W1 + 2*P(x@W2)) + b,  P = edge scatter-sum
// P applied in output feature space (64 then 40 dims).
// Edge scatter converted to CSR-by-dst gather (hierarchical scan build).
// CSR records packed (src,norm) 8B; prop unrolls gathers 8-wide for MLP.
// GEMMs: bf16 MFMA (16x16x32) with hi/lo split (fp32-accurate).
// ---------------------------------------------------------------------------

#define FIN1 128
#define HID 64
#define NCLS 40
#define UNR 8

typedef __attribute__((ext_vector_type(8))) short sx8;
typedef __attribute__((ext_vector_type(4))) float fx4;

__device__ inline unsigned short f2bf(float f) {
    unsigned u = __float_as_uint(f);
    unsigned r = (u + 0x7FFF + ((u >> 16) & 1)) >> 16;  // RNE
    return (unsigned short)r;
}
__device__ inline float bf2f(unsigned short h) {
    return __uint_as_float((unsigned)h << 16);
}

__global__ void k_count(const int* __restrict__ dst, int E, int* __restrict__ count) {
    int e = blockIdx.x * blockDim.x + threadIdx.x;
    if (e < E) atomicAdd(&count[dst[e]], 1);
}

// ---- hierarchical exclusive scan over count[N] ----
template <int EPT>
__global__ __launch_bounds__(256) void k_scan_part(const int* __restrict__ count, int N,
                                                   int* __restrict__ partial) {
    __shared__ int ws[4];
    int t = threadIdx.x;
    int lane = t & 63, w = t >> 6;
    int idx0 = blockIdx.x * 256 * EPT + t * EPT;
    int s = 0;
#pragma unroll
    for (int i = 0; i < EPT; ++i) {
        int idx = idx0 + i;
        if (idx < N) s += count[idx];
    }
#pragma unroll
    for (int d = 1; d < 64; d <<= 1) s += __shfl_xor(s, d);
    if (lane == 0) ws[w] = s;
    __syncthreads();
    if (t == 0) partial[blockIdx.x] = ws[0] + ws[1] + ws[2] + ws[3];
}

__global__ __launch_bounds__(256) void k_scan_mid(int* __restrict__ partial, int nb) {
    __shared__ int s[256];
    int t = threadIdx.x;
    int orig = (t < nb) ? partial[t] : 0;
    s[t] = orig;
    __syncthreads();
    for (int d = 1; d < 256; d <<= 1) {
        int v = (t >= d) ? s[t - d] : 0;
        __syncthreads();
        s[t] += v;
        __syncthreads();
    }
    if (t < nb) partial[t] = s[t] - orig;  // exclusive
}

template <int EPT>
__global__ __launch_bounds__(256) void k_scan_final(const int* __restrict__ count, int N,
                                                    const int* __restrict__ partial,
                                                    int* __restrict__ row_ptr,
                                                    int* __restrict__ cursor,
                                                    float* __restrict__ dis) {
    __shared__ int wsum[4];
    int t = threadIdx.x;
    int lane = t & 63, w = t >> 6;
    int idx0 = blockIdx.x * 256 * EPT + t * EPT;
    int c[EPT];
    int s = 0;
#pragma unroll
    for (int i = 0; i < EPT; ++i) {
        int idx = idx0 + i;
        c[i] = (idx < N) ? count[idx] : 0;
        s += c[i];
    }
    int incl = s;
#pragma unroll
    for (int d = 1; d < 64; d <<= 1) {
        int u = __shfl_up(incl, d);
        if (lane >= d) incl += u;
    }
    if (lane == 63) wsum[w] = incl;
    __syncthreads();
    int woff = 0;
    for (int i = 0; i < w; ++i) woff += wsum[i];
    int off = partial[blockIdx.x] + woff + (incl - s);
#pragma unroll
    for (int i = 0; i < EPT; ++i) {
        int idx = idx0 + i;
        if (idx < N) {
            row_ptr[idx] = off;
            cursor[idx] = off;
            dis[idx] = (c[i] > 0) ? rsqrtf((float)c[i]) : 0.0f;
            off += c[i];
            if (idx == N - 1) row_ptr[N] = off;
        }
    }
}

__global__ void k_fill(const int* __restrict__ src, const int* __restrict__ dst, int E,
                       const float* __restrict__ dis, int* __restrict__ cursor,
                       int2* __restrict__ csrp) {
    int e = blockIdx.x * blockDim.x + threadIdx.x;
    if (e < E) {
        int s = src[e];
        int d = dst[e];
        int pos = atomicAdd(&cursor[d], 1);
        csrp[pos] = make_int2(s, __float_as_int(-dis[s] * dis[d]));
    }
}

// Pre-swizzle W[3][FIN][FOE] (fp32) into MFMA B-fragment layout, hi/lo bf16:
//   frag[s][t][lane][i] = W[m][k][c],  k = s*32 + (lane>>4)*8 + i,
//   col = t*16 + (lane&15), m = col/FOE, c = col%FOE  (zero if col >= 3*FOE)
template <int NS, int T, int FIN, int FOE>
__global__ void k_wprep(const float* __restrict__ W, unsigned short* __restrict__ hi,
                        unsigned short* __restrict__ lo) {
    int idx = blockIdx.x * 256 + threadIdx.x;
    constexpr int total = NS * T * 64 * 8;
    if (idx >= total) return;
    int i = idx & 7;
    int l = (idx >> 3) & 63;
    int t = (idx >> 9) % T;
    int s = idx / (512 * T);
    int k = s * 32 + (l >> 4) * 8 + i;
    int col = t * 16 + (l & 15);
    float w = 0.0f;
    if (col < 3 * FOE) {
        int m = col / FOE;
        int c = col - m * FOE;
        w = W[((size_t)m * FIN + k) * FOE + c];
    }
    unsigned short h = f2bf(w);
    hi[idx] = h;
    lo[idx] = f2bf(w - bf2f(h));
}

// MFMA GEMM: C{0,1,2}[N,FOE] = A[N,FIN] @ W[m][FIN][FOE] (via pre-swizzled frags).
template <int FIN, int T, int NS, int FOE>
__global__ __launch_bounds__(256, 3) void k_gemm_mfma(
    const float* __restrict__ A, const unsigned short* __restrict__ Whi,
    const unsigned short* __restrict__ Wlo, float* __restrict__ C0,
    float* __restrict__ C1, float* __restrict__ C2, int N) {
    int tid = threadIdx.x;
    int w = tid >> 6, l = tid & 63;
    int row0 = blockIdx.x * 128 + w * 32;
    int rl = l & 15, kg = l >> 4;

    fx4 acc[2][T];
#pragma unroll
    for (int rt = 0; rt < 2; ++rt)
#pragma unroll
        for (int t = 0; t < T; ++t) acc[rt][t] = (fx4)0.0f;

    for (int s = 0; s < NS; ++s) {
        int k0 = s * 32 + kg * 8;
        sx8 ahi[2], alo[2];
#pragma unroll
        for (int rt = 0; rt < 2; ++rt) {
            int r = min(row0 + rt * 16 + rl, N - 1);
            const fx4* ap = (const fx4*)(A + (size_t)r * FIN + k0);
            fx4 a0 = ap[0];
            fx4 a1 = ap[1];
#pragma unroll
            for (int j = 0; j < 4; ++j) {
                unsigned short h0 = f2bf(a0[j]);
                unsigned short h1 = f2bf(a1[j]);
                ahi[rt][j] = (short)h0;
                ahi[rt][j + 4] = (short)h1;
                alo[rt][j] = (short)f2bf(a0[j] - bf2f(h0));
                alo[rt][j + 4] = (short)f2bf(a1[j] - bf2f(h1));
            }
        }
        const sx8* wh = (const sx8*)(Whi + ((size_t)(s * T) * 64 + l) * 8);
        const sx8* wl = (const sx8*)(Wlo + ((size_t)(s * T) * 64 + l) * 8);
#pragma unroll
        for (int t = 0; t < T; ++t) {
            sx8 bh = wh[t * 64];
            sx8 bl = wl[t * 64];
#pragma unroll
            for (int rt = 0; rt < 2; ++rt) {
                acc[rt][t] = __builtin_amdgcn_mfma_f32_16x16x32_bf16(ahi[rt], bh, acc[rt][t], 0, 0, 0);
                acc[rt][t] = __builtin_amdgcn_mfma_f32_16x16x32_bf16(ahi[rt], bl, acc[rt][t], 0, 0, 0);
                acc[rt][t] = __builtin_amdgcn_mfma_f32_16x16x32_bf16(alo[rt], bh, acc[rt][t], 0, 0, 0);
            }
        }
    }

#pragma unroll
    for (int rt = 0; rt < 2; ++rt)
#pragma unroll
        for (int t = 0; t < T; ++t) {
            int col = t * 16 + rl;
            int m = col / FOE;
            int cc = col - m * FOE;
            if (m < 3) {
                float* Cm = (m == 0) ? C0 : ((m == 1) ? C1 : C2);
#pragma unroll
                for (int j = 0; j < 4; ++j) {
                    int r = row0 + rt * 16 + kg * 4 + j;
                    if (r < N) Cm[(size_t)r * FOE + cc] = acc[rt][t][j];
                }
            }
        }
}

// CSR gather-prop with fused epilogue. One 64-lane wave per dst node, lane=feature.
// Edge records (src,norm) read wave-uniform (HW broadcast); gathers unrolled
// UNR-wide for memory-level parallelism. Tail edges get w=0 (order-preserving).
// MODE 0: out = o0 + 2*acc
// MODE 1: out = relu(o0 - o1 + acc + bias[f])
// MODE 2: z = o0 - o1 + acc + bias[f]; out = log_softmax(z) over F classes
template <int F, int MODE>
__global__ void k_prop(const int* __restrict__ row_ptr, const int2* __restrict__ csrp,
                       const float* __restrict__ in, const float* __restrict__ o0,
                       const float* __restrict__ o1, const float* __restrict__ bias,
                       float* __restrict__ out, int N) {
    int wid = (blockIdx.x * blockDim.x + threadIdx.x) >> 6;
    int lane = threadIdx.x & 63;
    if (wid >= N) return;
    int beg = row_ptr[wid];
    int end = row_ptr[wid + 1];
    float acc = 0.0f;
    for (int j = beg; j < end; j += UNR) {
        int ss[UNR];
        float ww[UNR];
#pragma unroll
        for (int i = 0; i < UNR; ++i) {
            int2 e = csrp[j + i];  // wave-uniform broadcast load (pad-safe)
            ss[i] = e.x;
            ww[i] = (j + i < end) ? __int_as_float(e.y) : 0.0f;
        }
#pragma unroll
        for (int i = 0; i < UNR; ++i) {
            float v = (lane < F) ? in[(size_t)ss[i] * F + lane] : 0.0f;
            acc = fmaf(ww[i], v, acc);
        }
    }
    size_t o = (size_t)wid * F + lane;
    if (MODE == 0) {
        if (lane < F) out[o] = o0[o] + 2.0f * acc;
    } else if (MODE == 1) {
        if (lane < F) {
            float z = o0[o] - o1[o] + acc + bias[lane];
            out[o] = fmaxf(z, 0.0f);
        }
    } else {
        float z = (lane < F) ? (o0[o] - o1[o] + acc + bias[lane]) : -INFINITY;
        float m = z;
#pragma unroll
        for (int d = 32; d; d >>= 1) m = fmaxf(m, __shfl_xor(m, d));
        float e = (lane < F) ? expf(z - m) : 0.0f;
        float l = e;
#pragma unroll
        for (int d = 32; d; d >>= 1) l += __shfl_xor(l, d);
        if (lane < F) out[o] = z - m - logf(l);
    }
}

extern "C" void kernel_launch(void* const* d_in, const int* in_sizes, int n_in,
                              void* d_out, int out_size, void* d_ws, size_t ws_size,
                              hipStream_t stream) {
    const float* x = (const float*)d_in[0];
    const int* ei = (const int*)d_in[1];
    const float* W1 = (const float*)d_in[2];
    const float* b1 = (const float*)d_in[3];
    const float* W2 = (const float*)d_in[4];
    const float* b2 = (const float*)d_in[5];
    float* out = (float*)d_out;

    const int N = in_sizes[0] / FIN1;  // 100000
    const int E = in_sizes[1] / 2;     // 1600000
    const int* src = ei;
    const int* dst = ei + E;

    // workspace carve (256B aligned)
    char* p = (char*)d_ws;
    auto alloc = [&](size_t bytes) -> void* {
        void* r = (void*)p;
        p += (bytes + 255) & ~(size_t)255;
        return r;
    };
    int* count = (int*)alloc((size_t)N * 4);
    int* row_ptr = (int*)alloc((size_t)(N + 1) * 4);
    int* cursor = (int*)alloc((size_t)N * 4);
    float* dis = (float*)alloc((size_t)N * 4);
    int* partial = (int*)alloc(256 * 4);
    int2* csrp = (int2*)alloc(((size_t)E + UNR) * 8);  // packed (src, norm) + pad
    float* buf0 = (float*)alloc((size_t)N * HID * 4);  // c0, later d0
    float* buf1 = (float*)alloc((size_t)N * HID * 4);  // ca, later da
    float* buf2 = (float*)alloc((size_t)N * HID * 4);  // cb, later db
    float* buf3 = (float*)alloc((size_t)N * HID * 4);  // s,  later s2
    float* buf4 = (float*)alloc((size_t)N * HID * 4);  // h
    // W fragment buffers (hi/lo bf16, B-frag layout)
    constexpr int W1FRAG = 4 * 12 * 64 * 8;  // 24576
    constexpr int W2FRAG = 2 * 8 * 64 * 8;   // 8192
    unsigned short* wf1h = (unsigned short*)alloc((size_t)W1FRAG * 2);
    unsigned short* wf1l = (unsigned short*)alloc((size_t)W1FRAG * 2);
    unsigned short* wf2h = (unsigned short*)alloc((size_t)W2FRAG * 2);
    unsigned short* wf2l = (unsigned short*)alloc((size_t)W2FRAG * 2);

    const int be = (E + 255) / 256;
    const int bg = (N + 127) / 128;       // MFMA gemm blocks (BM=128)
    const int bp = (N * 64 + 255) / 256;  // one wave per node
    constexpr int EPB = 256 * 8;
    const int nb = (N + EPB - 1) / EPB;   // 49 blocks for N=100000

    // ---- W fragment prep (independent of graph) ----
    k_wprep<4, 12, FIN1, HID><<<(W1FRAG + 255) / 256, 256, 0, stream>>>(W1, wf1h, wf1l);
    k_wprep<2, 8, HID, NCLS><<<(W2FRAG + 255) / 256, 256, 0, stream>>>(W2, wf2h, wf2l);

    // ---- graph structure: degree, CSR, norm ----
    hipMemsetAsync(count, 0, (size_t)N * 4, stream);
    hipMemsetAsync(csrp + E, 0, (size_t)UNR * 8, stream);  // zero pad records
    k_count<<<be, 256, 0, stream>>>(dst, E, count);
    k_scan_part<8><<<nb, 256, 0, stream>>>(count, N, partial);
    k_scan_mid<<<1, 256, 0, stream>>>(partial, nb);
    k_scan_final<8><<<nb, 256, 0, stream>>>(count, N, partial, row_ptr, cursor, dis);
    k_fill<<<be, 256, 0, stream>>>(src, dst, E, dis, cursor, csrp);

    // ---- layer 1: x[N,128] -> h[N,64] ----
    k_gemm_mfma<FIN1, 12, 4, HID><<<bg, 256, 0, stream>>>(x, wf1h, wf1l, buf0, buf1, buf2, N);
    // s = ca + 2*P(cb)
    k_prop<HID, 0><<<bp, 256, 0, stream>>>(row_ptr, csrp, buf2, buf1, nullptr, nullptr,
                                           buf3, N);
    // h = relu(c0 - cb + P(s) + b1)
    k_prop<HID, 1><<<bp, 256, 0, stream>>>(row_ptr, csrp, buf3, buf0, buf2, b1, buf4, N);

    // ---- layer 2: h[N,64] -> out[N,40] ----
    k_gemm_mfma<HID, 8, 2, NCLS><<<bg, 256, 0, stream>>>(buf4, wf2h, wf2l, buf0, buf1, buf2, N);
    // s2 = da + 2*P(db)
    k_prop<NCLS, 0><<<bp, 256, 0, stream>>>(row_ptr, csrp, buf2, buf1, nullptr, nullptr,
                                            buf3, N);
    // out = log_softmax(d0 - db + P(s2) + b2)
    k_prop<NCLS, 2><<<bp, 256, 0, stream>>>(row_ptr, csrp, buf3, buf0, buf2, b2, out, N);
}